// Round 2
// baseline (1242.539 us; speedup 1.0000x reference)
//
#include <hip/hip_runtime.h>
#include <cstdint>
#include <cstddef>

// Problem constants: B=32, L=2048, D=1024, E=2048
#define B_ 32
#define L_ 2048
#define D_ 1024
#define E_ 2048
// GEMM view: M = B*L = 65536 rows (b,l), N = D = 1024, K = E = 2048

typedef __attribute__((ext_vector_type(8))) short short8;
typedef __attribute__((ext_vector_type(16))) float f32x16;
typedef __attribute__((ext_vector_type(4))) unsigned int uint4v;

// ---- async global->LDS, 16B per lane; LDS dest = uniform base + lane*16 ----
__device__ __forceinline__ void async_copy16(const void* g, void* l) {
  __builtin_amdgcn_global_load_lds((const __attribute__((address_space(1))) void*)g,
                                   (__attribute__((address_space(3))) void*)l, 16, 0, 0);
}

// pack two fp32 -> bf16x2 (round-half-up: add 0x8000, take hi16) ~3 VALU
__device__ __forceinline__ unsigned int pack_bf16_2(float lo, float hi) {
  unsigned int ul = __builtin_bit_cast(unsigned int, lo) + 0x8000u;
  unsigned int uh = __builtin_bit_cast(unsigned int, hi) + 0x8000u;
  return (ul >> 16) | (uh & 0xFFFF0000u);
}

__device__ __forceinline__ float fast_tanh(float x) {
  // tanh(x) = 1 - 2/(exp(2x)+1); exp overflow -> +1, underflow -> -1 (correct)
  float e = __expf(2.0f * x);
  return 1.0f - 2.0f / (e + 1.0f);
}

// ---------------- kernel 1: s[b][i] = sum_d dec[b][d] * Ws[i][d] ------------
__global__ __launch_bounds__(256) void k_s(const float* __restrict__ dec,
                                           const float* __restrict__ Ws,
                                           float* __restrict__ s) {
  int wid = threadIdx.x >> 6, lane = threadIdx.x & 63;
  int out = blockIdx.x * 4 + wid;            // 0..32767
  int b = out >> 10, i = out & 1023;
  const float* dr = dec + b * D_;
  const float* wr = Ws + (size_t)i * D_;
  float acc = 0.f;
#pragma unroll
  for (int c = 0; c < 4; ++c) {
    int d0 = c * 256 + lane * 4;
    float4 x = *(const float4*)(dr + d0);
    float4 w = *(const float4*)(wr + d0);
    acc += x.x * w.x + x.y * w.y + x.z * w.z + x.w * w.w;
  }
#pragma unroll
  for (int off = 32; off >= 1; off >>= 1) acc += __shfl_xor(acc, off, 64);
  if (lane == 0) s[out] = acc;
}

// ---------------- kernel 2: W_h fp32 -> bf16 (2M elements) ------------------
__global__ __launch_bounds__(256) void k_cvt(const float* __restrict__ src,
                                             unsigned short* __restrict__ dst) {
  size_t i = ((size_t)blockIdx.x * 256 + threadIdx.x) * 8;
  float4 a = *(const float4*)(src + i);
  float4 b = *(const float4*)(src + i + 4);
  uint4v p;
  p.x = pack_bf16_2(a.x, a.y);
  p.y = pack_bf16_2(a.z, a.w);
  p.z = pack_bf16_2(b.x, b.y);
  p.w = pack_bf16_2(b.z, b.w);
  *(uint4v*)(dst + i) = p;
}

// ---------------- kernel 3: fused GEMM + tanh + v-dot -----------------------
// scores[m] = sum_n v[n] * tanh(s[b][n] + sum_k enc[m][k]*Whb[n][k]),  m=(b,l)
// Block tile 128(M)x128(N), BK=32; 128 threads = 2 waves, each wave 64x128.
// MFMA: 32x32x16 bf16 (2495 TF ubench vs 2176 for 16x16x32).
// A (enc) stays fp32 in LDS, packed to bf16 at fragment-read (3 VALU/pair);
// pack cost amortized over 8 B-tiles per A-frag (was 4 in R1).
__global__ __launch_bounds__(128, 2) void k_gemm(const float* __restrict__ enc,
                                                 const unsigned short* __restrict__ whb,
                                                 const float* __restrict__ sbias,
                                                 const float* __restrict__ vvec,
                                                 float* __restrict__ scores) {
  __shared__ alignas(16) float As[128 * 32];          // 16 KB fp32, xor-swizzled 16B units
  __shared__ alignas(16) unsigned short Bs[128 * 32]; // 8 KB bf16, xor-swizzled 16B units

  const int tid = threadIdx.x;
  const int wid = tid >> 6;   // 0..1 = waveM
  const int lane = tid & 63;

  const int flat = blockIdx.x;
  const int nt = flat & 7;          // 8 n-tiles consecutive -> enc L2/L3 reuse
  const int mt = flat >> 3;
  const int m_base = mt * 128, n_base = nt * 128;
  const int b_idx = m_base >> 11;   // 128 | 2048 -> b uniform per block

  // --- staging source addressing (global address carries the LDS xor-swizzle)
  // A chunk = 8 rows x 128 B (32 fp32): lane -> row l>>3, slot l&7,
  //   fetch 16B-unit g = (l&7) ^ ((l>>3)&7)
  const int aRowL = lane >> 3;
  const int aColF = ((lane & 7) ^ (aRowL & 7)) * 4;   // in floats
  // B chunk = 16 rows x 64 B (32 bf16): lane -> row l>>2, slot l&3,
  //   fetch 16B-unit g = (l&3) ^ ((l>>2)&3)
  const int bRowL = lane >> 2;
  const int bColH = ((lane & 3) ^ (bRowL & 3)) * 8;   // in bf16 elems

  const float* gA = enc + (size_t)(m_base + wid * 64 + aRowL) * E_ + aColF;
  const unsigned short* gB = whb + (size_t)(n_base + wid * 64 + bRowL) * E_ + bColH;

  // --- precomputed swizzled fragment read pointers (loop-invariant) ---
  const int col = lane & 31;   // MFMA row/col within 32
  const int h = lane >> 5;     // k-half
  const unsigned short* bptr[4][2];
#pragma unroll
  for (int ni = 0; ni < 4; ++ni)
#pragma unroll
    for (int ks = 0; ks < 2; ++ks) {
      int r = ni * 32 + col;
      int u = ks * 2 + h;
      bptr[ni][ks] = &Bs[r * 32 + ((u ^ (r & 3)) * 8)];
    }
  const float* aptr[2][2][2];
#pragma unroll
  for (int mi = 0; mi < 2; ++mi)
#pragma unroll
    for (int ks = 0; ks < 2; ++ks)
#pragma unroll
      for (int j = 0; j < 2; ++j) {
        int r = wid * 64 + mi * 32 + col;
        int u = ks * 4 + h * 2 + j;
        aptr[mi][ks][j] = &As[r * 32 + ((u ^ (r & 7)) * 4)];
      }

  f32x16 acc[2][4] = {};

  for (int kk = 0; kk < E_; kk += 32) {
    __syncthreads();  // previous iteration's LDS reads done
#pragma unroll
    for (int it = 0; it < 8; ++it)
      async_copy16(gA + (size_t)(it * 8) * E_ + kk, &As[(wid * 64 + it * 8) * 32]);
#pragma unroll
    for (int it = 0; it < 4; ++it)
      async_copy16(gB + (size_t)(it * 16) * E_ + kk, &Bs[(wid * 64 + it * 16) * 32]);
    __syncthreads();  // compiler drains vmcnt(0) before barrier -> LDS ready

#pragma unroll
    for (int ks = 0; ks < 2; ++ks) {
      short8 bf[4];
#pragma unroll
      for (int ni = 0; ni < 4; ++ni) bf[ni] = *(const short8*)bptr[ni][ks];
#pragma unroll
      for (int mi = 0; mi < 2; ++mi) {
        float4 f0 = *(const float4*)aptr[mi][ks][0];
        float4 f1 = *(const float4*)aptr[mi][ks][1];
        uint4v pa;
        pa.x = pack_bf16_2(f0.x, f0.y);
        pa.y = pack_bf16_2(f0.z, f0.w);
        pa.z = pack_bf16_2(f1.x, f1.y);
        pa.w = pack_bf16_2(f1.z, f1.w);
        short8 af = __builtin_bit_cast(short8, pa);
#pragma unroll
        for (int ni = 0; ni < 4; ++ni)
          acc[mi][ni] = __builtin_amdgcn_mfma_f32_32x32x16_bf16(af, bf[ni], acc[mi][ni], 0, 0, 0);
      }
    }
  }

  // --- epilogue: partial = sum over this block's 128 n of v[n]*tanh(s+h) ---
  // 32x32 C/D layout (m74/m101): col = lane&31, row = (reg&3)+8*(reg>>2)+4*(lane>>5)
  float vv[4], sv[4];
#pragma unroll
  for (int ni = 0; ni < 4; ++ni) {
    int n = n_base + ni * 32 + col;
    vv[ni] = vvec[n];
    sv[ni] = sbias[b_idx * D_ + n];
  }
#pragma unroll
  for (int mi = 0; mi < 2; ++mi) {
#pragma unroll
    for (int reg = 0; reg < 16; ++reg) {
      float sum = 0.f;
#pragma unroll
      for (int ni = 0; ni < 4; ++ni)
        sum += vv[ni] * fast_tanh(sv[ni] + acc[mi][ni][reg]);
      sum += __shfl_xor(sum, 1, 64);
      sum += __shfl_xor(sum, 2, 64);
      sum += __shfl_xor(sum, 4, 64);
      sum += __shfl_xor(sum, 8, 64);
      sum += __shfl_xor(sum, 16, 64);
      if (col == 0)
        atomicAdd(&scores[m_base + wid * 64 + mi * 32 + (reg & 3) + 8 * (reg >> 2) + h * 4], sum);
    }
  }
}

// ---------------- kernel 4: softmax over L per b (in-place) -----------------
__global__ __launch_bounds__(256) void k_softmax(float* __restrict__ sc) {
  int b = blockIdx.x, tid = threadIdx.x;
  int lane = tid & 63, wid = tid >> 6;
  float* row = sc + (size_t)b * L_;
  float vals[8];
  float mx = -1e30f;
#pragma unroll
  for (int j = 0; j < 8; ++j) { vals[j] = row[tid + j * 256]; mx = fmaxf(mx, vals[j]); }
#pragma unroll
  for (int off = 32; off >= 1; off >>= 1) mx = fmaxf(mx, __shfl_xor(mx, off, 64));
  __shared__ float redm[4], reds[4];
  if (lane == 0) redm[wid] = mx;
  __syncthreads();
  mx = fmaxf(fmaxf(redm[0], redm[1]), fmaxf(redm[2], redm[3]));
  float sum = 0.f;
#pragma unroll
  for (int j = 0; j < 8; ++j) { vals[j] = __expf(vals[j] - mx); sum += vals[j]; }
#pragma unroll
  for (int off = 32; off >= 1; off >>= 1) sum += __shfl_xor(sum, off, 64);
  if (lane == 0) reds[wid] = sum;
  __syncthreads();
  sum = reds[0] + reds[1] + reds[2] + reds[3];
  float inv = 1.0f / sum;
#pragma unroll
  for (int j = 0; j < 8; ++j) row[tid + j * 256] = vals[j] * inv;
}

// ---------------- kernel 5: ctx[b][e] = sum_l attn[b][l] * enc[b][l][e] -----
// grid (16 l-chunks of 128, 32 b); 256 threads cover E=2048 as 2x float4 each
__global__ __launch_bounds__(256) void k_ctx(const float* __restrict__ enc,
                                             const float* __restrict__ attn,
                                             float* __restrict__ ctx) {
  int b = blockIdx.y, lc = blockIdx.x;
  int t = threadIdx.x;
  __shared__ float aw[128];
  if (t < 128) aw[t] = attn[(size_t)b * L_ + lc * 128 + t];
  __syncthreads();
  const float* base = enc + ((size_t)b * L_ + (size_t)lc * 128) * E_;
  float4 a0 = make_float4(0.f, 0.f, 0.f, 0.f);
  float4 a1 = make_float4(0.f, 0.f, 0.f, 0.f);
#pragma unroll 2
  for (int l = 0; l < 128; ++l) {
    float w = aw[l];
    const float* r = base + (size_t)l * E_;
    float4 x0 = *(const float4*)(r + t * 4);
    float4 x1 = *(const float4*)(r + 1024 + t * 4);
    a0.x += w * x0.x; a0.y += w * x0.y; a0.z += w * x0.z; a0.w += w * x0.w;
    a1.x += w * x1.x; a1.y += w * x1.y; a1.z += w * x1.z; a1.w += w * x1.w;
  }
  float* cb = ctx + (size_t)b * E_;
  atomicAdd(cb + t * 4 + 0, a0.x);
  atomicAdd(cb + t * 4 + 1, a0.y);
  atomicAdd(cb + t * 4 + 2, a0.z);
  atomicAdd(cb + t * 4 + 3, a0.w);
  atomicAdd(cb + 1024 + t * 4 + 0, a1.x);
  atomicAdd(cb + 1024 + t * 4 + 1, a1.y);
  atomicAdd(cb + 1024 + t * 4 + 2, a1.z);
  atomicAdd(cb + 1024 + t * 4 + 3, a1.w);
}

extern "C" void kernel_launch(void* const* d_in, const int* in_sizes, int n_in,
                              void* d_out, int out_size, void* d_ws, size_t ws_size,
                              hipStream_t stream) {
  const float* dec = (const float*)d_in[0];  // [32,1024]
  const float* enc = (const float*)d_in[1];  // [32,2048,2048]
  const float* Ws  = (const float*)d_in[2];  // [1024,1024]
  const float* Wh  = (const float*)d_in[3];  // [1024,2048]
  const float* v   = (const float*)d_in[4];  // [1024]

  float* ctx  = (float*)d_out;                   // [32,2048]
  float* attn = (float*)d_out + B_ * E_;         // [32,2048]; also scores scratch

  // workspace: W_h in bf16 (4 MB) + s (128 KB)
  unsigned short* whb = (unsigned short*)d_ws;
  float* sbuf = (float*)((char*)d_ws + (size_t)D_ * E_ * sizeof(unsigned short));

  // zero ctx + scores (both accumulated via atomics)
  hipMemsetAsync(d_out, 0, (size_t)out_size * sizeof(float), stream);

  k_s<<<dim3((B_ * D_) / 4), dim3(256), 0, stream>>>(dec, Ws, sbuf);
  k_cvt<<<dim3((D_ * E_) / (256 * 8)), dim3(256), 0, stream>>>(Wh, whb);
  k_gemm<<<dim3((B_ * L_ / 128) * (D_ / 128)), dim3(128), 0, stream>>>(enc, whb, sbuf, v, attn);
  k_softmax<<<dim3(B_), dim3(256), 0, stream>>>(attn);
  k_ctx<<<dim3(L_ / 128, B_), dim3(256), 0, stream>>>(enc, attn, ctx);
}

// Round 3
// 1145.598 us; speedup vs baseline: 1.0846x; 1.0846x over previous
//
#include <hip/hip_runtime.h>
#include <cstdint>
#include <cstddef>

// Problem constants: B=32, L=2048, D=1024, E=2048
#define B_ 32
#define L_ 2048
#define D_ 1024
#define E_ 2048
// GEMM view: M = B*L = 65536 rows (b,l), N = D = 1024, K = E = 2048

typedef __attribute__((ext_vector_type(8))) short short8;
typedef __attribute__((ext_vector_type(16))) float f32x16;
typedef __attribute__((ext_vector_type(4))) unsigned int uint4v;

// ---- async global->LDS, 16B per lane; LDS dest = uniform base + lane*16 ----
__device__ __forceinline__ void async_copy16(const void* g, void* l) {
  __builtin_amdgcn_global_load_lds((const __attribute__((address_space(1))) void*)g,
                                   (__attribute__((address_space(3))) void*)l, 16, 0, 0);
}

// pack two fp32 -> bf16x2 (round-half-up: add 0x8000, take hi16) ~3 VALU
__device__ __forceinline__ unsigned int pack_bf16_2(float lo, float hi) {
  unsigned int ul = __builtin_bit_cast(unsigned int, lo) + 0x8000u;
  unsigned int uh = __builtin_bit_cast(unsigned int, hi) + 0x8000u;
  return (ul >> 16) | (uh & 0xFFFF0000u);
}

__device__ __forceinline__ float fast_tanh(float x) {
  // tanh(x) = 1 - 2/(exp(2x)+1); exp overflow -> +1, underflow -> -1 (correct)
  float e = __expf(2.0f * x);
  return 1.0f - 2.0f / (e + 1.0f);
}

// ---------------- kernel 1: s[b][i] = sum_d dec[b][d] * Ws[i][d] ------------
__global__ __launch_bounds__(256) void k_s(const float* __restrict__ dec,
                                           const float* __restrict__ Ws,
                                           float* __restrict__ s) {
  int wid = threadIdx.x >> 6, lane = threadIdx.x & 63;
  int out = blockIdx.x * 4 + wid;            // 0..32767
  int b = out >> 10, i = out & 1023;
  const float* dr = dec + b * D_;
  const float* wr = Ws + (size_t)i * D_;
  float acc = 0.f;
#pragma unroll
  for (int c = 0; c < 4; ++c) {
    int d0 = c * 256 + lane * 4;
    float4 x = *(const float4*)(dr + d0);
    float4 w = *(const float4*)(wr + d0);
    acc += x.x * w.x + x.y * w.y + x.z * w.z + x.w * w.w;
  }
#pragma unroll
  for (int off = 32; off >= 1; off >>= 1) acc += __shfl_xor(acc, off, 64);
  if (lane == 0) s[out] = acc;
}

// ---------------- kernel 2: W_h fp32 -> bf16 (2M elements) ------------------
__global__ __launch_bounds__(256) void k_cvt(const float* __restrict__ src,
                                             unsigned short* __restrict__ dst) {
  size_t i = ((size_t)blockIdx.x * 256 + threadIdx.x) * 8;
  float4 a = *(const float4*)(src + i);
  float4 b = *(const float4*)(src + i + 4);
  uint4v p;
  p.x = pack_bf16_2(a.x, a.y);
  p.y = pack_bf16_2(a.z, a.w);
  p.z = pack_bf16_2(b.x, b.y);
  p.w = pack_bf16_2(b.z, b.w);
  *(uint4v*)(dst + i) = p;
}

// ---------------- kernel 3: fused GEMM + tanh + v-dot -----------------------
// scores[m] = sum_n v[n] * tanh(s[b][n] + sum_k enc[m][k]*Whb[n][k]),  m=(b,l)
// Block tile 128(M)x128(N), BK=32; 128 threads = 2 waves, each wave 64x128.
// MFMA: 32x32x16 bf16. A (enc) stays fp32 in LDS, packed to bf16 at
// fragment-read; pack amortized over 8 B-tiles per A-frag.
// A LDS: 128 rows x 128 B, 16B units xor-swizzled by (row&7).
// B LDS: 64 lines x 128 B (2 rows/line), units xor-swizzled by (line&7) --
//        keeps every b128 phase on all 32 banks (64-B rows caused 2x conflicts).
__global__ __launch_bounds__(128, 2) void k_gemm(const float* __restrict__ enc,
                                                 const unsigned short* __restrict__ whb,
                                                 const float* __restrict__ sbias,
                                                 const float* __restrict__ vvec,
                                                 float* __restrict__ scores) {
  __shared__ alignas(16) float As[128 * 32];          // 16 KB fp32
  __shared__ alignas(16) unsigned short Bs[128 * 32]; // 8 KB bf16 (64 lines x 64 shorts)

  const int tid = threadIdx.x;
  const int wid = tid >> 6;   // 0..1
  const int lane = tid & 63;

  // XCD swizzle: all 8 N-tiles of one M-tile share flat%8 -> same XCD L2.
  const int flat = blockIdx.x;
  const int nt = (flat >> 3) & 7;
  const int mt = (flat & 7) | ((flat >> 6) << 3);
  const int m_base = mt * 128, n_base = nt * 128;
  const int b_idx = m_base >> 11;   // 128 | 2048 -> b uniform per block

  // --- staging source addressing (global address carries the LDS swizzle) ---
  // A chunk = 8 rows x 128 B: lane -> row l>>3, unit (l&7)^((l>>3)&7)
  const int aRowL = lane >> 3;
  const int aColF = ((lane & 7) ^ (aRowL & 7)) * 4;   // in floats
  const float* gA = enc + (size_t)(m_base + wid * 64 + aRowL) * E_ + aColF;
  // B chunk = 8 lines (16 rows): lane -> line l>>3, su = l&7,
  //   unit = su ^ (line&7); row = 2*line + (unit>>2); k-off = (unit&3)*8
  {
  }
  const int bUnit = (lane & 7) ^ ((lane >> 3) & 7);
  const int bRow0 = 2 * (lane >> 3) + (bUnit >> 2);
  const int bKoff = (bUnit & 3) * 8;
  const unsigned short* gB = whb + (size_t)(n_base + wid * 64 + bRow0) * E_ + bKoff;

  // --- precomputed swizzled fragment read pointers (loop-invariant) ---
  const int col = lane & 31;   // MFMA row/col within 32
  const int h = lane >> 5;     // k-half
  const unsigned short* bptr[4][2];
#pragma unroll
  for (int ni = 0; ni < 4; ++ni)
#pragma unroll
    for (int ks = 0; ks < 2; ++ks) {
      int line = ni * 16 + (col >> 1);
      int unit = (col & 1) * 4 + ks * 2 + h;
      bptr[ni][ks] = &Bs[line * 64 + ((unit ^ (line & 7)) * 8)];
    }
  const float* aptr[2][2][2];
#pragma unroll
  for (int mi = 0; mi < 2; ++mi)
#pragma unroll
    for (int ks = 0; ks < 2; ++ks)
#pragma unroll
      for (int j = 0; j < 2; ++j) {
        int r = wid * 64 + mi * 32 + col;
        int u = ks * 4 + h * 2 + j;
        aptr[mi][ks][j] = &As[r * 32 + ((u ^ (r & 7)) * 4)];
      }

  f32x16 acc[2][4] = {};

  for (int kk = 0; kk < E_; kk += 32) {
    __syncthreads();  // previous iteration's LDS reads done
#pragma unroll
    for (int it = 0; it < 8; ++it)
      async_copy16(gA + (size_t)(it * 8) * E_ + kk, &As[(wid * 64 + it * 8) * 32]);
#pragma unroll
    for (int it = 0; it < 4; ++it)
      async_copy16(gB + (size_t)(it * 16) * E_ + kk, &Bs[(wid * 64 + it * 16) * 32]);
    __syncthreads();  // compiler drains vmcnt(0) before barrier -> LDS ready

#pragma unroll
    for (int ks = 0; ks < 2; ++ks) {
      short8 bf[4];
#pragma unroll
      for (int ni = 0; ni < 4; ++ni) bf[ni] = *(const short8*)bptr[ni][ks];
#pragma unroll
      for (int mi = 0; mi < 2; ++mi) {
        float4 f0 = *(const float4*)aptr[mi][ks][0];
        float4 f1 = *(const float4*)aptr[mi][ks][1];
        uint4v pa;
        pa.x = pack_bf16_2(f0.x, f0.y);
        pa.y = pack_bf16_2(f0.z, f0.w);
        pa.z = pack_bf16_2(f1.x, f1.y);
        pa.w = pack_bf16_2(f1.z, f1.w);
        short8 af = __builtin_bit_cast(short8, pa);
#pragma unroll
        for (int ni = 0; ni < 4; ++ni)
          acc[mi][ni] = __builtin_amdgcn_mfma_f32_32x32x16_bf16(af, bf[ni], acc[mi][ni], 0, 0, 0);
      }
    }
  }

  // --- epilogue: partial = sum over this block's 128 n of v[n]*tanh(s+h) ---
  // 32x32 C/D layout (m74/m101): col = lane&31, row = (reg&3)+8*(reg>>2)+4*(lane>>5)
  float vv[4], sv[4];
#pragma unroll
  for (int ni = 0; ni < 4; ++ni) {
    int n = n_base + ni * 32 + col;
    vv[ni] = vvec[n];
    sv[ni] = sbias[b_idx * D_ + n];
  }
#pragma unroll
  for (int mi = 0; mi < 2; ++mi) {
#pragma unroll
    for (int reg = 0; reg < 16; ++reg) {
      float sum = 0.f;
#pragma unroll
      for (int ni = 0; ni < 4; ++ni)
        sum += vv[ni] * fast_tanh(sv[ni] + acc[mi][ni][reg]);
      sum += __shfl_xor(sum, 1, 64);
      sum += __shfl_xor(sum, 2, 64);
      sum += __shfl_xor(sum, 4, 64);
      sum += __shfl_xor(sum, 8, 64);
      sum += __shfl_xor(sum, 16, 64);
      if (col == 0)
        atomicAdd(&scores[m_base + wid * 64 + mi * 32 + (reg & 3) + 8 * (reg >> 2) + h * 4], sum);
    }
  }
}

// ---------------- kernel 4: softmax over L per b (in-place) -----------------
__global__ __launch_bounds__(256) void k_softmax(float* __restrict__ sc) {
  int b = blockIdx.x, tid = threadIdx.x;
  int lane = tid & 63, wid = tid >> 6;
  float* row = sc + (size_t)b * L_;
  float vals[8];
  float mx = -1e30f;
#pragma unroll
  for (int j = 0; j < 8; ++j) { vals[j] = row[tid + j * 256]; mx = fmaxf(mx, vals[j]); }
#pragma unroll
  for (int off = 32; off >= 1; off >>= 1) mx = fmaxf(mx, __shfl_xor(mx, off, 64));
  __shared__ float redm[4], reds[4];
  if (lane == 0) redm[wid] = mx;
  __syncthreads();
  mx = fmaxf(fmaxf(redm[0], redm[1]), fmaxf(redm[2], redm[3]));
  float sum = 0.f;
#pragma unroll
  for (int j = 0; j < 8; ++j) { vals[j] = __expf(vals[j] - mx); sum += vals[j]; }
#pragma unroll
  for (int off = 32; off >= 1; off >>= 1) sum += __shfl_xor(sum, off, 64);
  if (lane == 0) reds[wid] = sum;
  __syncthreads();
  sum = reds[0] + reds[1] + reds[2] + reds[3];
  float inv = 1.0f / sum;
#pragma unroll
  for (int j = 0; j < 8; ++j) row[tid + j * 256] = vals[j] * inv;
}

// ---------------- kernel 5: ctx[b][e] = sum_l attn[b][l] * enc[b][l][e] -----
// grid (16 l-chunks of 128, 32 b); 256 threads cover E=2048 as 2x float4 each
__global__ __launch_bounds__(256) void k_ctx(const float* __restrict__ enc,
                                             const float* __restrict__ attn,
                                             float* __restrict__ ctx) {
  int b = blockIdx.y, lc = blockIdx.x;
  int t = threadIdx.x;
  __shared__ float aw[128];
  if (t < 128) aw[t] = attn[(size_t)b * L_ + lc * 128 + t];
  __syncthreads();
  const float* base = enc + ((size_t)b * L_ + (size_t)lc * 128) * E_;
  float4 a0 = make_float4(0.f, 0.f, 0.f, 0.f);
  float4 a1 = make_float4(0.f, 0.f, 0.f, 0.f);
#pragma unroll 2
  for (int l = 0; l < 128; ++l) {
    float w = aw[l];
    const float* r = base + (size_t)l * E_;
    float4 x0 = *(const float4*)(r + t * 4);
    float4 x1 = *(const float4*)(r + 1024 + t * 4);
    a0.x += w * x0.x; a0.y += w * x0.y; a0.z += w * x0.z; a0.w += w * x0.w;
    a1.x += w * x1.x; a1.y += w * x1.y; a1.z += w * x1.z; a1.w += w * x1.w;
  }
  float* cb = ctx + (size_t)b * E_;
  atomicAdd(cb + t * 4 + 0, a0.x);
  atomicAdd(cb + t * 4 + 1, a0.y);
  atomicAdd(cb + t * 4 + 2, a0.z);
  atomicAdd(cb + t * 4 + 3, a0.w);
  atomicAdd(cb + 1024 + t * 4 + 0, a1.x);
  atomicAdd(cb + 1024 + t * 4 + 1, a1.y);
  atomicAdd(cb + 1024 + t * 4 + 2, a1.z);
  atomicAdd(cb + 1024 + t * 4 + 3, a1.w);
}

extern "C" void kernel_launch(void* const* d_in, const int* in_sizes, int n_in,
                              void* d_out, int out_size, void* d_ws, size_t ws_size,
                              hipStream_t stream) {
  const float* dec = (const float*)d_in[0];  // [32,1024]
  const float* enc = (const float*)d_in[1];  // [32,2048,2048]
  const float* Ws  = (const float*)d_in[2];  // [1024,1024]
  const float* Wh  = (const float*)d_in[3];  // [1024,2048]
  const float* v   = (const float*)d_in[4];  // [1024]

  float* ctx  = (float*)d_out;                   // [32,2048]
  float* attn = (float*)d_out + B_ * E_;         // [32,2048]; also scores scratch

  // workspace: W_h in bf16 (4 MB) + s (128 KB)
  unsigned short* whb = (unsigned short*)d_ws;
  float* sbuf = (float*)((char*)d_ws + (size_t)D_ * E_ * sizeof(unsigned short));

  // zero ctx + scores (both accumulated via atomics)
  hipMemsetAsync(d_out, 0, (size_t)out_size * sizeof(float), stream);

  k_s<<<dim3((B_ * D_) / 4), dim3(256), 0, stream>>>(dec, Ws, sbuf);
  k_cvt<<<dim3((D_ * E_) / (256 * 8)), dim3(256), 0, stream>>>(Wh, whb);
  k_gemm<<<dim3((B_ * L_ / 128) * (D_ / 128)), dim3(128), 0, stream>>>(enc, whb, sbuf, v, attn);
  k_softmax<<<dim3(B_), dim3(256), 0, stream>>>(attn);
  k_ctx<<<dim3(L_ / 128, B_), dim3(256), 0, stream>>>(enc, attn, ctx);
}